// Round 1
// baseline (217.662 us; speedup 1.0000x reference)
//
#include <hip/hip_runtime.h>

#define N_NODES 50000
#define EPS 1e-6f
#define NPAD 50048      // N rounded up to 64
#define CAP 64          // fixed per-node neighbor capacity (max real deg ~45, Poisson(16))

// ---------------- Workspace layout (ints then floats) ----------------
// cnt   : NPAD ints   (zeroed each call; per-node degree counters)
// ssrc  : NPAD*64 ints (fixed-stride per-node neighbor lists, row n at n*64)
// mean1 : NPAD*64 floats
// g     : NPAD*64 floats
//
// NUMERICS CONTRACT: absmax pinned at 0.03125 empirically.
//  - neighbor-sum ORDER is free across nodes/edges only in *which thread*
//    computes it; per-node per-feature the ADD SEQUENCE is fixed:
//    groups-of-4 (v0+v1)+(v2+v3) ascending, tail sequential. Loads may be
//    batched/reordered freely (pure reads). Within-node neighbor-list order
//    is atomic-nondeterministic (was already so via csr_kernel's lpos race).
//    mean = acc*dinv, dinv = 1/(deg+EPS); val = acc*dinv + b2;
//    softmax: lane-xor butterfly 8,4,2,1 then (x+z)+(y+w); (val-mx)-logf(sm).
//  - GEMMs: acc init (bias/0), fmaf ascending k, one chain per output.
// SCHEDULE CONTRACT (round-6): constant-trip k-loops containing global loads
// MUST carry #pragma unroll 1 (else full unroll -> VGPR 256 -> scratch spill).
// GATHER CONTRACT (round-8): NO per-edge LDS atomics in the float gathers.
// GRID CONTRACT (round-9): latency-bound build kernels need >=256 blocks.
// MLP CONTRACT (round-11): batch 8 row-loads in flight per wave before
// consuming (Little's law at L3 latency); adds stay in contract order.
// BUILD CONTRACT (round-12): single-pass fixed-capacity fill. One global
// atomicAdd per edge on cnt[dst]; ssrc row stride = CAP = 64. Replaces the
// 4-kernel bucket/scan/fill/CSR pipeline (3 edge passes -> 1).

#define COMP(v, j) ((j) == 0 ? (v).x : (j) == 1 ? (v).y : (j) == 2 ? (v).z : (v).w)

// ---- Single-pass neighbor-list fill ----
__global__ __launch_bounds__(256) void fill_kernel(
    const int* __restrict__ src, const int* __restrict__ dst,
    int* __restrict__ cnt, int* __restrict__ ssrc, int E) {
  int e = blockIdx.x * 256 + threadIdx.x;
  if (e >= E) return;
  int d = dst[e];
  int s = src[e];
  int pos = atomicAdd(&cnt[d], 1);
  if (pos < CAP) ssrc[((size_t)d << 6) + pos] = s;  // guard: no OOB write ever
}

// Batched 8-in-flight accumulate of edges [j0, j0+8) — adds in contract order.
#define GATHER8(SRCPTR, SARR, J0)                                         \
  {                                                                       \
    float4 v[8];                                                          \
    _Pragma("unroll")                                                     \
    for (int j = 0; j < 8; j++)                                           \
      v[j] = ((const float4*)((SRCPTR) + (size_t)SARR[(J0) + j] * 64))[l16]; \
    acc.x += (v[0].x + v[1].x) + (v[2].x + v[3].x);                       \
    acc.y += (v[0].y + v[1].y) + (v[2].y + v[3].y);                       \
    acc.z += (v[0].z + v[1].z) + (v[2].z + v[3].z);                       \
    acc.w += (v[0].w + v[1].w) + (v[2].w + v[3].w);                       \
    acc.x += (v[4].x + v[5].x) + (v[6].x + v[7].x);                       \
    acc.y += (v[4].y + v[5].y) + (v[6].y + v[7].y);                       \
    acc.z += (v[4].z + v[5].z) + (v[6].z + v[7].z);                       \
    acc.w += (v[4].w + v[5].w) + (v[6].w + v[7].w);                       \
  }

// ---- Gather 1: mean1[n] = mean of x[neighbors] ----
__global__ __launch_bounds__(256) void gather1_kernel(
    const float* __restrict__ x, const int* __restrict__ cnt,
    const int* __restrict__ ssrc, float* __restrict__ mean1) {
  int t = threadIdx.x;
  int lane = t & 63;
  int sub = lane >> 4;
  int l16 = lane & 15;
  int node = blockIdx.x * 16 + ((t >> 6) << 2) + sub;
  int srcLane = sub << 4;
  int b = node << 6;
  int e = b + cnt[node];
  float4 acc = {0.f, 0.f, 0.f, 0.f};
  for (int base = b; base < e; base += 16) {
    int rem = e - base; if (rem > 16) rem = 16;
    int idx = (l16 < rem) ? ssrc[base + l16] : 0;
    if (rem == 16) {
      int s[16];
#pragma unroll
      for (int j = 0; j < 16; j++) s[j] = __shfl(idx, srcLane + j, 64);
      GATHER8(x, s, 0)
      GATHER8(x, s, 8)
    } else {
      int j = 0;
      for (; j + 4 <= rem; j += 4) {
        int s0 = __shfl(idx, srcLane + j, 64);
        int s1 = __shfl(idx, srcLane + j + 1, 64);
        int s2 = __shfl(idx, srcLane + j + 2, 64);
        int s3 = __shfl(idx, srcLane + j + 3, 64);
        float4 v0 = ((const float4*)(x + (size_t)s0 * 64))[l16];
        float4 v1 = ((const float4*)(x + (size_t)s1 * 64))[l16];
        float4 v2 = ((const float4*)(x + (size_t)s2 * 64))[l16];
        float4 v3 = ((const float4*)(x + (size_t)s3 * 64))[l16];
        acc.x += (v0.x + v1.x) + (v2.x + v3.x);
        acc.y += (v0.y + v1.y) + (v2.y + v3.y);
        acc.z += (v0.z + v1.z) + (v2.z + v3.z);
        acc.w += (v0.w + v1.w) + (v2.w + v3.w);
      }
      for (; j < rem; j++) {
        int s = __shfl(idx, srcLane + j, 64);
        float4 v = ((const float4*)(x + (size_t)s * 64))[l16];
        acc.x += v.x; acc.y += v.y; acc.z += v.z; acc.w += v.w;
      }
    }
  }
  float dinv = 1.0f / ((float)(e - b) + EPS);
  float4 o4;
  o4.x = acc.x * dinv; o4.y = acc.y * dinv;
  o4.z = acc.z * dinv; o4.w = acc.w * dinv;
  ((float4*)(mean1 + (size_t)node * 64))[l16] = o4;
}

// ---- Fused MLP (round-7 verbatim) ----
__global__ __launch_bounds__(256, 3) void mlp_fused_kernel(
    const float* __restrict__ mean1, const float* __restrict__ W1,
    const float* __restrict__ b1, const float* __restrict__ W2,
    float* __restrict__ g) {
  __shared__ float sM[64][68];
  __shared__ float sH[64][132];
  int t = threadIdx.x;
  int row0 = blockIdx.x * 64;

  {
    const float4* M4 = (const float4*)(mean1 + (size_t)row0 * 64);
#pragma unroll
    for (int i = 0; i < 4; i++) {
      int idx = t + 256 * i;
      *(float4*)&sM[idx >> 4][(idx & 15) << 2] = M4[idx];
    }
  }
  __syncthreads();

  int tc = t & 15;
  int tr = t >> 4;

  {  // GEMM1 + relu -> sH
    int c = tc << 3;
    int r = tr << 2;
    float acc[4][8];
    float4 bA = *(const float4*)(b1 + c);
    float4 bB = *(const float4*)(b1 + c + 4);
#pragma unroll
    for (int i = 0; i < 4; i++) {
      acc[i][0] = bA.x; acc[i][1] = bA.y; acc[i][2] = bA.z; acc[i][3] = bA.w;
      acc[i][4] = bB.x; acc[i][5] = bB.y; acc[i][6] = bB.z; acc[i][7] = bB.w;
    }
#pragma unroll 1
    for (int k = 0; k < 64; k += 4) {
      float4 a[4];
#pragma unroll
      for (int i = 0; i < 4; i++) a[i] = *(const float4*)&sM[r + i][k];
      float4 wA[4], wB[4];
#pragma unroll
      for (int j = 0; j < 4; j++) {
        const float* wrow = W1 + (size_t)(k + j) * 128 + c;
        wA[j] = *(const float4*)wrow;
        wB[j] = *(const float4*)(wrow + 4);
      }
#pragma unroll
      for (int j = 0; j < 4; j++) {
#pragma unroll
        for (int i = 0; i < 4; i++) {
          float av = COMP(a[i], j);
          acc[i][0] = fmaf(av, wA[j].x, acc[i][0]);
          acc[i][1] = fmaf(av, wA[j].y, acc[i][1]);
          acc[i][2] = fmaf(av, wA[j].z, acc[i][2]);
          acc[i][3] = fmaf(av, wA[j].w, acc[i][3]);
          acc[i][4] = fmaf(av, wB[j].x, acc[i][4]);
          acc[i][5] = fmaf(av, wB[j].y, acc[i][5]);
          acc[i][6] = fmaf(av, wB[j].z, acc[i][6]);
          acc[i][7] = fmaf(av, wB[j].w, acc[i][7]);
        }
      }
    }
#pragma unroll
    for (int i = 0; i < 4; i++) {
      float4 h0, h1v;
      h0.x = fmaxf(acc[i][0], 0.f); h0.y = fmaxf(acc[i][1], 0.f);
      h0.z = fmaxf(acc[i][2], 0.f); h0.w = fmaxf(acc[i][3], 0.f);
      h1v.x = fmaxf(acc[i][4], 0.f); h1v.y = fmaxf(acc[i][5], 0.f);
      h1v.z = fmaxf(acc[i][6], 0.f); h1v.w = fmaxf(acc[i][7], 0.f);
      *(float4*)&sH[r + i][c] = h0;
      *(float4*)&sH[r + i][c + 4] = h1v;
    }
  }
  __syncthreads();

  {  // GEMM2 -> g
    int c = tc << 2;
    int r = tr << 2;
    float acc[4][4];
#pragma unroll
    for (int i = 0; i < 4; i++)
      acc[i][0] = acc[i][1] = acc[i][2] = acc[i][3] = 0.f;
#pragma unroll 1
    for (int k = 0; k < 128; k += 4) {
      float4 a[4];
#pragma unroll
      for (int i = 0; i < 4; i++) a[i] = *(const float4*)&sH[r + i][k];
      float4 w[4];
#pragma unroll
      for (int j = 0; j < 4; j++)
        w[j] = *(const float4*)(W2 + (size_t)(k + j) * 64 + c);
#pragma unroll
      for (int j = 0; j < 4; j++) {
#pragma unroll
        for (int i = 0; i < 4; i++) {
          float av = COMP(a[i], j);
          acc[i][0] = fmaf(av, w[j].x, acc[i][0]);
          acc[i][1] = fmaf(av, w[j].y, acc[i][1]);
          acc[i][2] = fmaf(av, w[j].z, acc[i][2]);
          acc[i][3] = fmaf(av, w[j].w, acc[i][3]);
        }
      }
    }
#pragma unroll
    for (int i = 0; i < 4; i++) {
      int row = row0 + r + i;
      if (row < N_NODES) {
        float4 o4;
        o4.x = acc[i][0]; o4.y = acc[i][1]; o4.z = acc[i][2]; o4.w = acc[i][3];
        *(float4*)(g + (size_t)row * 64 + c) = o4;
      }
    }
  }
}

// ---- Gather 2 + bias + log_softmax ----
__global__ __launch_bounds__(256) void gather2_kernel(
    const float* __restrict__ g, const int* __restrict__ cnt,
    const int* __restrict__ ssrc, const float* __restrict__ b2,
    float* __restrict__ out) {
  int t = threadIdx.x;
  int lane = t & 63;
  int sub = lane >> 4;
  int l16 = lane & 15;
  int node = blockIdx.x * 16 + ((t >> 6) << 2) + sub;
  int srcLane = sub << 4;
  int b = node << 6;
  int e = b + cnt[node];
  float4 acc = {0.f, 0.f, 0.f, 0.f};
  for (int base = b; base < e; base += 16) {
    int rem = e - base; if (rem > 16) rem = 16;
    int idx = (l16 < rem) ? ssrc[base + l16] : 0;
    if (rem == 16) {
      int s[16];
#pragma unroll
      for (int j = 0; j < 16; j++) s[j] = __shfl(idx, srcLane + j, 64);
      GATHER8(g, s, 0)
      GATHER8(g, s, 8)
    } else {
      int j = 0;
      for (; j + 4 <= rem; j += 4) {
        int s0 = __shfl(idx, srcLane + j, 64);
        int s1 = __shfl(idx, srcLane + j + 1, 64);
        int s2 = __shfl(idx, srcLane + j + 2, 64);
        int s3 = __shfl(idx, srcLane + j + 3, 64);
        float4 v0 = ((const float4*)(g + (size_t)s0 * 64))[l16];
        float4 v1 = ((const float4*)(g + (size_t)s1 * 64))[l16];
        float4 v2 = ((const float4*)(g + (size_t)s2 * 64))[l16];
        float4 v3 = ((const float4*)(g + (size_t)s3 * 64))[l16];
        acc.x += (v0.x + v1.x) + (v2.x + v3.x);
        acc.y += (v0.y + v1.y) + (v2.y + v3.y);
        acc.z += (v0.z + v1.z) + (v2.z + v3.z);
        acc.w += (v0.w + v1.w) + (v2.w + v3.w);
      }
      for (; j < rem; j++) {
        int s = __shfl(idx, srcLane + j, 64);
        float4 v = ((const float4*)(g + (size_t)s * 64))[l16];
        acc.x += v.x; acc.y += v.y; acc.z += v.z; acc.w += v.w;
      }
    }
  }
  float dinv = 1.0f / ((float)(e - b) + EPS);
  float4 b2v = ((const float4*)b2)[l16];
  float4 val;
  val.x = acc.x * dinv + b2v.x;
  val.y = acc.y * dinv + b2v.y;
  val.z = acc.z * dinv + b2v.z;
  val.w = acc.w * dinv + b2v.w;

  float4 m = val;
#pragma unroll
  for (int o = 8; o > 0; o >>= 1) {
    m.x = fmaxf(m.x, __shfl_xor(m.x, o, 64));
    m.y = fmaxf(m.y, __shfl_xor(m.y, o, 64));
    m.z = fmaxf(m.z, __shfl_xor(m.z, o, 64));
    m.w = fmaxf(m.w, __shfl_xor(m.w, o, 64));
  }
  float mx = fmaxf(fmaxf(m.x, m.z), fmaxf(m.y, m.w));

  float4 ex;
  ex.x = __expf(val.x - mx);
  ex.y = __expf(val.y - mx);
  ex.z = __expf(val.z - mx);
  ex.w = __expf(val.w - mx);
#pragma unroll
  for (int o = 8; o > 0; o >>= 1) {
    ex.x += __shfl_xor(ex.x, o, 64);
    ex.y += __shfl_xor(ex.y, o, 64);
    ex.z += __shfl_xor(ex.z, o, 64);
    ex.w += __shfl_xor(ex.w, o, 64);
  }
  float sm = (ex.x + ex.z) + (ex.y + ex.w);

  float ls = logf(sm);
  float4 o4;
  o4.x = (val.x - mx) - ls;
  o4.y = (val.y - mx) - ls;
  o4.z = (val.z - mx) - ls;
  o4.w = (val.w - mx) - ls;
  ((float4*)(out + (size_t)node * 64))[l16] = o4;
}

extern "C" void kernel_launch(void* const* d_in, const int* in_sizes, int n_in,
                              void* d_out, int out_size, void* d_ws, size_t ws_size,
                              hipStream_t stream) {
  const float* x   = (const float*)d_in[0];
  const int*   src = (const int*)d_in[1];
  const int*   dst = (const int*)d_in[2];
  const float* W1  = (const float*)d_in[3];
  const float* b1  = (const float*)d_in[4];
  const float* W2  = (const float*)d_in[5];
  const float* b2  = (const float*)d_in[6];
  float* out = (float*)d_out;
  int E = in_sizes[1];

  int* cnt  = (int*)d_ws;                       // NPAD
  int* ssrc = cnt + NPAD;                       // NPAD*64
  float* mean1 = (float*)(ssrc + (size_t)NPAD * 64);  // NPAD*64
  float* g     = mean1 + (size_t)NPAD * 64;     // NPAD*64

  hipMemsetAsync(cnt, 0, NPAD * sizeof(int), stream);
  fill_kernel<<<(E + 255) / 256, 256, 0, stream>>>(src, dst, cnt, ssrc, E);
  gather1_kernel<<<N_NODES / 16, 256, 0, stream>>>(x, cnt, ssrc, mean1);
  mlp_fused_kernel<<<NPAD / 64, 256, 0, stream>>>(mean1, W1, b1, W2, g);
  gather2_kernel<<<N_NODES / 16, 256, 0, stream>>>(g, cnt, ssrc, b2, out);
}

// Round 2
// 193.417 us; speedup vs baseline: 1.1254x; 1.1254x over previous
//
#include <hip/hip_runtime.h>

#define N_NODES 50000
#define EPS 1e-6f
#define NPAD 50048      // N rounded up to 64
#define CAP 64          // fixed per-node neighbor capacity (max real deg ~45, Poisson(16))

// ---- Two-pass radix build geometry (round-13) ----
#define NBKT 512        // buckets
#define NPB 98          // nodes per bucket; NBKT*NPB = 50176 >= NPAD
#define NROWS (NBKT * NPB)
#define BCAP 2048       // per-bucket edge capacity (= 1<<11); expected 1568, +12 sigma
#define CHUNK_A 3072    // edges per bucketize block -> 261 blocks (grid contract: >=256)

// ---------------- Workspace layout (ints then floats) ----------------
// bcur   : NBKT ints      (zeroed each call; bucket cursors / final bucket counts)
// packed : NBKT*BCAP ints ((src<<8)|dlocal, grouped by bucket)
// cnt    : NROWS ints     (per-node degree, written by rows_kernel)
// ssrc   : NROWS*64 ints  (fixed-stride per-node neighbor lists, row n at n*64)
// mean1  : NPAD*64 floats
// g      : NPAD*64 floats
//
// NUMERICS CONTRACT: absmax pinned at 0.03125 empirically.
//  - neighbor-sum ORDER is free across nodes/edges only in *which thread*
//    computes it; per-node per-feature the ADD SEQUENCE is fixed:
//    groups-of-4 (v0+v1)+(v2+v3) ascending, tail sequential. Loads may be
//    batched/reordered freely (pure reads). Within-node neighbor-list order
//    is atomic-nondeterministic (was already so in every prior build).
//    mean = acc*dinv, dinv = 1/(deg+EPS); val = acc*dinv + b2;
//    softmax: lane-xor butterfly 8,4,2,1 then (x+z)+(y+w); (val-mx)-logf(sm).
//  - GEMMs: acc init (bias/0), fmaf ascending k, one chain per output.
// SCHEDULE CONTRACT (round-6): constant-trip k-loops containing global loads
// MUST carry #pragma unroll 1 (else full unroll -> VGPR 256 -> scratch spill).
// GATHER CONTRACT (round-8): NO per-edge LDS atomics in the float gathers.
// GRID CONTRACT (round-9): latency-bound build kernels need >=256 blocks.
// MLP CONTRACT (round-11): batch 8 row-loads in flight per wave before
// consuming (Little's law at L3 latency); adds stay in contract order.
// BUILD CONTRACT (round-13): scattered 4B global writes cost a full 64B
// HBM line each (round-12 measured 48 MB writes for 3.2 MB logical).
// All bulk writes must be block-coalesced: partition first (LDS-staged
// runs), then materialize rows from LDS images with full-line stores.

#define COMP(v, j) ((j) == 0 ? (v).x : (j) == 1 ? (v).y : (j) == 2 ? (v).z : (v).w)

// ---- Pass A: partition edges into 512 buckets of 98 nodes ----
__global__ __launch_bounds__(256) void bucketize_kernel(
    const int* __restrict__ src, const int* __restrict__ dst,
    int* __restrict__ bcur, int* __restrict__ packed, int E) {
  __shared__ int lcnt[NBKT];
  __shared__ int lbase[NBKT];
  int t = threadIdx.x;
  lcnt[t] = 0; lcnt[t + 256] = 0;
  __syncthreads();
  int base = blockIdx.x * CHUNK_A;
  int end = base + CHUNK_A; if (end > E) end = E;
  for (int e = base + t; e < end; e += 256) atomicAdd(&lcnt[dst[e] / NPB], 1);
  __syncthreads();
  {  // one global reservation per touched bucket (thread t owns buckets t, t+256)
    int c0 = lcnt[t], c1 = lcnt[t + 256];
    lbase[t]       = c0 ? atomicAdd(&bcur[t], c0) : 0;
    lbase[t + 256] = c1 ? atomicAdd(&bcur[t + 256], c1) : 0;
    lcnt[t] = 0; lcnt[t + 256] = 0;  // reuse as local cursors (own slots only)
  }
  __syncthreads();
  for (int e = base + t; e < end; e += 256) {
    int d = dst[e];
    int b = d / NPB;                 // compile-time magic-mul division
    int pos = lbase[b] + atomicAdd(&lcnt[b], 1);
    if (pos < BCAP)                  // guard: never OOB
      packed[(b << 11) + pos] = (src[e] << 8) | (d - b * NPB);
  }
}

// ---- Pass B: materialize per-node rows from LDS image, full-line stores ----
__global__ __launch_bounds__(256) void rows_kernel(
    const int* __restrict__ bcur, const int* __restrict__ packed,
    int* __restrict__ cnt, int* __restrict__ ssrc) {
  __shared__ int lout[NPB * 64];   // 25088 B bucket row image (garbage slots never read)
  __shared__ int lcnt[NPB];
  int t = threadIdx.x;
  int b = blockIdx.x;
  if (t < NPB) lcnt[t] = 0;
  __syncthreads();
  int count = bcur[b]; if (count > BCAP) count = BCAP;
  const int* pk = packed + (b << 11);
  for (int i = t; i < count; i += 256) {
    int p = pk[i];
    int dl = p & 0xff;
    int pos = atomicAdd(&lcnt[dl], 1);
    if (pos < CAP) lout[(dl << 6) + pos] = p >> 8;
  }
  __syncthreads();
  int4* d4 = (int4*)(ssrc + (size_t)b * (NPB * 64));
  const int4* s4 = (const int4*)lout;
  for (int i = t; i < NPB * 16; i += 256) d4[i] = s4[i];
  if (t < NPB) {
    int c = lcnt[t]; if (c > CAP) c = CAP;
    cnt[b * NPB + t] = c;
  }
}

// Batched 8-in-flight accumulate of edges [j0, j0+8) — adds in contract order.
#define GATHER8(SRCPTR, SARR, J0)                                         \
  {                                                                       \
    float4 v[8];                                                          \
    _Pragma("unroll")                                                     \
    for (int j = 0; j < 8; j++)                                           \
      v[j] = ((const float4*)((SRCPTR) + (size_t)SARR[(J0) + j] * 64))[l16]; \
    acc.x += (v[0].x + v[1].x) + (v[2].x + v[3].x);                       \
    acc.y += (v[0].y + v[1].y) + (v[2].y + v[3].y);                       \
    acc.z += (v[0].z + v[1].z) + (v[2].z + v[3].z);                       \
    acc.w += (v[0].w + v[1].w) + (v[2].w + v[3].w);                       \
    acc.x += (v[4].x + v[5].x) + (v[6].x + v[7].x);                       \
    acc.y += (v[4].y + v[5].y) + (v[6].y + v[7].y);                       \
    acc.z += (v[4].z + v[5].z) + (v[6].z + v[7].z);                       \
    acc.w += (v[4].w + v[5].w) + (v[6].w + v[7].w);                       \
  }

// ---- Gather 1: mean1[n] = mean of x[neighbors] ----
__global__ __launch_bounds__(256) void gather1_kernel(
    const float* __restrict__ x, const int* __restrict__ cnt,
    const int* __restrict__ ssrc, float* __restrict__ mean1) {
  int t = threadIdx.x;
  int lane = t & 63;
  int sub = lane >> 4;
  int l16 = lane & 15;
  int node = blockIdx.x * 16 + ((t >> 6) << 2) + sub;
  int srcLane = sub << 4;
  int b = node << 6;
  int e = b + cnt[node];
  float4 acc = {0.f, 0.f, 0.f, 0.f};
  for (int base = b; base < e; base += 16) {
    int rem = e - base; if (rem > 16) rem = 16;
    int idx = (l16 < rem) ? ssrc[base + l16] : 0;
    if (rem == 16) {
      int s[16];
#pragma unroll
      for (int j = 0; j < 16; j++) s[j] = __shfl(idx, srcLane + j, 64);
      GATHER8(x, s, 0)
      GATHER8(x, s, 8)
    } else {
      int j = 0;
      for (; j + 4 <= rem; j += 4) {
        int s0 = __shfl(idx, srcLane + j, 64);
        int s1 = __shfl(idx, srcLane + j + 1, 64);
        int s2 = __shfl(idx, srcLane + j + 2, 64);
        int s3 = __shfl(idx, srcLane + j + 3, 64);
        float4 v0 = ((const float4*)(x + (size_t)s0 * 64))[l16];
        float4 v1 = ((const float4*)(x + (size_t)s1 * 64))[l16];
        float4 v2 = ((const float4*)(x + (size_t)s2 * 64))[l16];
        float4 v3 = ((const float4*)(x + (size_t)s3 * 64))[l16];
        acc.x += (v0.x + v1.x) + (v2.x + v3.x);
        acc.y += (v0.y + v1.y) + (v2.y + v3.y);
        acc.z += (v0.z + v1.z) + (v2.z + v3.z);
        acc.w += (v0.w + v1.w) + (v2.w + v3.w);
      }
      for (; j < rem; j++) {
        int s = __shfl(idx, srcLane + j, 64);
        float4 v = ((const float4*)(x + (size_t)s * 64))[l16];
        acc.x += v.x; acc.y += v.y; acc.z += v.z; acc.w += v.w;
      }
    }
  }
  float dinv = 1.0f / ((float)(e - b) + EPS);
  float4 o4;
  o4.x = acc.x * dinv; o4.y = acc.y * dinv;
  o4.z = acc.z * dinv; o4.w = acc.w * dinv;
  ((float4*)(mean1 + (size_t)node * 64))[l16] = o4;
}

// ---- Fused MLP (round-7 verbatim) ----
__global__ __launch_bounds__(256, 3) void mlp_fused_kernel(
    const float* __restrict__ mean1, const float* __restrict__ W1,
    const float* __restrict__ b1, const float* __restrict__ W2,
    float* __restrict__ g) {
  __shared__ float sM[64][68];
  __shared__ float sH[64][132];
  int t = threadIdx.x;
  int row0 = blockIdx.x * 64;

  {
    const float4* M4 = (const float4*)(mean1 + (size_t)row0 * 64);
#pragma unroll
    for (int i = 0; i < 4; i++) {
      int idx = t + 256 * i;
      *(float4*)&sM[idx >> 4][(idx & 15) << 2] = M4[idx];
    }
  }
  __syncthreads();

  int tc = t & 15;
  int tr = t >> 4;

  {  // GEMM1 + relu -> sH
    int c = tc << 3;
    int r = tr << 2;
    float acc[4][8];
    float4 bA = *(const float4*)(b1 + c);
    float4 bB = *(const float4*)(b1 + c + 4);
#pragma unroll
    for (int i = 0; i < 4; i++) {
      acc[i][0] = bA.x; acc[i][1] = bA.y; acc[i][2] = bA.z; acc[i][3] = bA.w;
      acc[i][4] = bB.x; acc[i][5] = bB.y; acc[i][6] = bB.z; acc[i][7] = bB.w;
    }
#pragma unroll 1
    for (int k = 0; k < 64; k += 4) {
      float4 a[4];
#pragma unroll
      for (int i = 0; i < 4; i++) a[i] = *(const float4*)&sM[r + i][k];
      float4 wA[4], wB[4];
#pragma unroll
      for (int j = 0; j < 4; j++) {
        const float* wrow = W1 + (size_t)(k + j) * 128 + c;
        wA[j] = *(const float4*)wrow;
        wB[j] = *(const float4*)(wrow + 4);
      }
#pragma unroll
      for (int j = 0; j < 4; j++) {
#pragma unroll
        for (int i = 0; i < 4; i++) {
          float av = COMP(a[i], j);
          acc[i][0] = fmaf(av, wA[j].x, acc[i][0]);
          acc[i][1] = fmaf(av, wA[j].y, acc[i][1]);
          acc[i][2] = fmaf(av, wA[j].z, acc[i][2]);
          acc[i][3] = fmaf(av, wA[j].w, acc[i][3]);
          acc[i][4] = fmaf(av, wB[j].x, acc[i][4]);
          acc[i][5] = fmaf(av, wB[j].y, acc[i][5]);
          acc[i][6] = fmaf(av, wB[j].z, acc[i][6]);
          acc[i][7] = fmaf(av, wB[j].w, acc[i][7]);
        }
      }
    }
#pragma unroll
    for (int i = 0; i < 4; i++) {
      float4 h0, h1v;
      h0.x = fmaxf(acc[i][0], 0.f); h0.y = fmaxf(acc[i][1], 0.f);
      h0.z = fmaxf(acc[i][2], 0.f); h0.w = fmaxf(acc[i][3], 0.f);
      h1v.x = fmaxf(acc[i][4], 0.f); h1v.y = fmaxf(acc[i][5], 0.f);
      h1v.z = fmaxf(acc[i][6], 0.f); h1v.w = fmaxf(acc[i][7], 0.f);
      *(float4*)&sH[r + i][c] = h0;
      *(float4*)&sH[r + i][c + 4] = h1v;
    }
  }
  __syncthreads();

  {  // GEMM2 -> g
    int c = tc << 2;
    int r = tr << 2;
    float acc[4][4];
#pragma unroll
    for (int i = 0; i < 4; i++)
      acc[i][0] = acc[i][1] = acc[i][2] = acc[i][3] = 0.f;
#pragma unroll 1
    for (int k = 0; k < 128; k += 4) {
      float4 a[4];
#pragma unroll
      for (int i = 0; i < 4; i++) a[i] = *(const float4*)&sH[r + i][k];
      float4 w[4];
#pragma unroll
      for (int j = 0; j < 4; j++)
        w[j] = *(const float4*)(W2 + (size_t)(k + j) * 64 + c);
#pragma unroll
      for (int j = 0; j < 4; j++) {
#pragma unroll
        for (int i = 0; i < 4; i++) {
          float av = COMP(a[i], j);
          acc[i][0] = fmaf(av, w[j].x, acc[i][0]);
          acc[i][1] = fmaf(av, w[j].y, acc[i][1]);
          acc[i][2] = fmaf(av, w[j].z, acc[i][2]);
          acc[i][3] = fmaf(av, w[j].w, acc[i][3]);
        }
      }
    }
#pragma unroll
    for (int i = 0; i < 4; i++) {
      int row = row0 + r + i;
      if (row < N_NODES) {
        float4 o4;
        o4.x = acc[i][0]; o4.y = acc[i][1]; o4.z = acc[i][2]; o4.w = acc[i][3];
        *(float4*)(g + (size_t)row * 64 + c) = o4;
      }
    }
  }
}

// ---- Gather 2 + bias + log_softmax ----
__global__ __launch_bounds__(256) void gather2_kernel(
    const float* __restrict__ g, const int* __restrict__ cnt,
    const int* __restrict__ ssrc, const float* __restrict__ b2,
    float* __restrict__ out) {
  int t = threadIdx.x;
  int lane = t & 63;
  int sub = lane >> 4;
  int l16 = lane & 15;
  int node = blockIdx.x * 16 + ((t >> 6) << 2) + sub;
  int srcLane = sub << 4;
  int b = node << 6;
  int e = b + cnt[node];
  float4 acc = {0.f, 0.f, 0.f, 0.f};
  for (int base = b; base < e; base += 16) {
    int rem = e - base; if (rem > 16) rem = 16;
    int idx = (l16 < rem) ? ssrc[base + l16] : 0;
    if (rem == 16) {
      int s[16];
#pragma unroll
      for (int j = 0; j < 16; j++) s[j] = __shfl(idx, srcLane + j, 64);
      GATHER8(g, s, 0)
      GATHER8(g, s, 8)
    } else {
      int j = 0;
      for (; j + 4 <= rem; j += 4) {
        int s0 = __shfl(idx, srcLane + j, 64);
        int s1 = __shfl(idx, srcLane + j + 1, 64);
        int s2 = __shfl(idx, srcLane + j + 2, 64);
        int s3 = __shfl(idx, srcLane + j + 3, 64);
        float4 v0 = ((const float4*)(g + (size_t)s0 * 64))[l16];
        float4 v1 = ((const float4*)(g + (size_t)s1 * 64))[l16];
        float4 v2 = ((const float4*)(g + (size_t)s2 * 64))[l16];
        float4 v3 = ((const float4*)(g + (size_t)s3 * 64))[l16];
        acc.x += (v0.x + v1.x) + (v2.x + v3.x);
        acc.y += (v0.y + v1.y) + (v2.y + v3.y);
        acc.z += (v0.z + v1.z) + (v2.z + v3.z);
        acc.w += (v0.w + v1.w) + (v2.w + v3.w);
      }
      for (; j < rem; j++) {
        int s = __shfl(idx, srcLane + j, 64);
        float4 v = ((const float4*)(g + (size_t)s * 64))[l16];
        acc.x += v.x; acc.y += v.y; acc.z += v.z; acc.w += v.w;
      }
    }
  }
  float dinv = 1.0f / ((float)(e - b) + EPS);
  float4 b2v = ((const float4*)b2)[l16];
  float4 val;
  val.x = acc.x * dinv + b2v.x;
  val.y = acc.y * dinv + b2v.y;
  val.z = acc.z * dinv + b2v.z;
  val.w = acc.w * dinv + b2v.w;

  float4 m = val;
#pragma unroll
  for (int o = 8; o > 0; o >>= 1) {
    m.x = fmaxf(m.x, __shfl_xor(m.x, o, 64));
    m.y = fmaxf(m.y, __shfl_xor(m.y, o, 64));
    m.z = fmaxf(m.z, __shfl_xor(m.z, o, 64));
    m.w = fmaxf(m.w, __shfl_xor(m.w, o, 64));
  }
  float mx = fmaxf(fmaxf(m.x, m.z), fmaxf(m.y, m.w));

  float4 ex;
  ex.x = __expf(val.x - mx);
  ex.y = __expf(val.y - mx);
  ex.z = __expf(val.z - mx);
  ex.w = __expf(val.w - mx);
#pragma unroll
  for (int o = 8; o > 0; o >>= 1) {
    ex.x += __shfl_xor(ex.x, o, 64);
    ex.y += __shfl_xor(ex.y, o, 64);
    ex.z += __shfl_xor(ex.z, o, 64);
    ex.w += __shfl_xor(ex.w, o, 64);
  }
  float sm = (ex.x + ex.z) + (ex.y + ex.w);

  float ls = logf(sm);
  float4 o4;
  o4.x = (val.x - mx) - ls;
  o4.y = (val.y - mx) - ls;
  o4.z = (val.z - mx) - ls;
  o4.w = (val.w - mx) - ls;
  ((float4*)(out + (size_t)node * 64))[l16] = o4;
}

extern "C" void kernel_launch(void* const* d_in, const int* in_sizes, int n_in,
                              void* d_out, int out_size, void* d_ws, size_t ws_size,
                              hipStream_t stream) {
  const float* x   = (const float*)d_in[0];
  const int*   src = (const int*)d_in[1];
  const int*   dst = (const int*)d_in[2];
  const float* W1  = (const float*)d_in[3];
  const float* b1  = (const float*)d_in[4];
  const float* W2  = (const float*)d_in[5];
  const float* b2  = (const float*)d_in[6];
  float* out = (float*)d_out;
  int E = in_sizes[1];

  int* bcur   = (int*)d_ws;                         // NBKT
  int* packed = bcur + NBKT;                        // NBKT*BCAP
  int* cnt    = packed + (size_t)NBKT * BCAP;       // NROWS
  int* ssrc   = cnt + NROWS;                        // NROWS*64
  float* mean1 = (float*)(ssrc + (size_t)NROWS * 64);  // NPAD*64
  float* g     = mean1 + (size_t)NPAD * 64;            // NPAD*64

  hipMemsetAsync(bcur, 0, NBKT * sizeof(int), stream);
  bucketize_kernel<<<(E + CHUNK_A - 1) / CHUNK_A, 256, 0, stream>>>(
      src, dst, bcur, packed, E);
  rows_kernel<<<NBKT, 256, 0, stream>>>(bcur, packed, cnt, ssrc);
  gather1_kernel<<<N_NODES / 16, 256, 0, stream>>>(x, cnt, ssrc, mean1);
  mlp_fused_kernel<<<NPAD / 64, 256, 0, stream>>>(mean1, W1, b1, W2, g);
  gather2_kernel<<<N_NODES / 16, 256, 0, stream>>>(g, cnt, ssrc, b2, out);
}